// Round 10
// baseline (605.735 us; speedup 1.0000x reference)
//
#include <hip/hip_runtime.h>

typedef unsigned int u32;
typedef unsigned short u16;
typedef unsigned long long u64;
typedef u16 u16x8 __attribute__((ext_vector_type(8)));
typedef u16 u16x4 __attribute__((ext_vector_type(4)));
typedef __bf16 bf16x8 __attribute__((ext_vector_type(8)));
typedef __bf16 bf16x4v __attribute__((ext_vector_type(4)));
typedef float f32x4 __attribute__((ext_vector_type(4)));
typedef float f32x2 __attribute__((ext_vector_type(2)));

#define B_SZ 32
#define S_SZ 128
#define T_SZ 127
#define DK 128
#define SKILL 256
#define SQTR 64    /* skills per block (4-way split) */
#define RL 136     /* hS row pitch (u16): 128 + 8 pad */
#define PP 68      /* part row pitch (f32): 64 + 4 pad */
#define NPAIR 8    /* (b,t) pairs per aux block; 4064 = 508*8 */
#define SPIN_CAP (1 << 18)

/* repacked-weight offsets (floats), chunk-major WT[(k4*128+o)*4+j] */
#define W1T_OFF 0        /* 96 chunks  */
#define WLT_OFF 49152    /* 128 chunks */
#define WGT_OFF 114688   /* 128 chunks */
#define WFT_OFF 180224   /* 96 chunks  */
#define WPT_OFF 229376   /* 64 chunks  */
#define WT_TOTAL 262144

__device__ __forceinline__ u16x4 cvt4(f32x4 v) {
    return __builtin_bit_cast(u16x4, __builtin_convertvector(v, bf16x4v));
}
__device__ __forceinline__ u16x8 cvt8(f32x4 a, f32x4 b) {
    u16x4 x = cvt4(a), y = cvt4(b);
    u16x8 r;
    r[0]=x[0]; r[1]=x[1]; r[2]=x[2]; r[3]=x[3];
    r[4]=y[0]; r[5]=y[1]; r[6]=y[2]; r[7]=y[3];
    return r;
}
__device__ __forceinline__ u16 bfu(float x) {
    return __builtin_bit_cast(u16, (__bf16)x);
}
__device__ __forceinline__ float sigm(float x) {
    float e = __builtin_amdgcn_exp2f(-1.44269504f * x);
    return __builtin_amdgcn_rcpf(1.f + e);
}
__device__ __forceinline__ float tanh_f(float x) {
    float e = __builtin_amdgcn_exp2f(-2.88539008f * x);
    return 2.f * __builtin_amdgcn_rcpf(1.f + e) - 1.f;
}
__device__ __forceinline__ f32x4 mfma16(u16x8 a, u16x8 bb, f32x4 c) {
    return __builtin_amdgcn_mfma_f32_16x16x32_bf16(
        __builtin_bit_cast(bf16x8, a), __builtin_bit_cast(bf16x8, bb), c, 0, 0, 0);
}
__device__ __forceinline__ float pval(u64 p) {
    return __builtin_bit_cast(float, (u32)p);
}
__device__ __forceinline__ float dot4(f32x4 w, f32x4 x) {
    return w[0] * x[0] + w[1] * x[1] + w[2] * x[2] + w[3] * x[3];
}

// ---------------------------------------------------------------------------
// Kernel P: repack W1/Wl/Wg/Wf/Wp into chunk-major WT so that aux weight
// loads are lane-consecutive (8 L1 lines/wave-load instead of 64).
// ---------------------------------------------------------------------------
__global__ __launch_bounds__(256) void k_prep(
    const float* __restrict__ W1, const float* __restrict__ Wl,
    const float* __restrict__ Wg, const float* __restrict__ Wf,
    const float* __restrict__ Wp, float* __restrict__ WT)
{
    int i = blockIdx.x * 256 + threadIdx.x;      // < 262144
    int j = i & 3, o = (i >> 2) & 127, k4 = i >> 9;
    float v;
    if (k4 < 96)        v = W1[o * 384 + 4 * k4 + j];
    else if (k4 < 224)  v = Wl[o * 512 + 4 * (k4 - 96) + j];
    else if (k4 < 352)  v = Wg[o * 512 + 4 * (k4 - 224) + j];
    else if (k4 < 448)  v = Wf[o * 384 + 4 * (k4 - 352) + j];
    else                v = Wp[o * 256 + 4 * (k4 - 448) + j];
    WT[i] = v;
}

// ---------------------------------------------------------------------------
// Kernel B (fused le+pre): per block, compute le for 9 pairs (p0-1..p0+7)
// into LDS (bit-identical to old k_le), then the gate pre-activations for
// 8 pairs. All weight loads coalesced via WT. x rows wave-uniform scalar.
// t==0 lp via exact mask-multiply (adds 0.0 -> bit-identical).
// ---------------------------------------------------------------------------
__global__ __launch_bounds__(128) void k_pre(
    const int* __restrict__ eid, const int* __restrict__ atime,
    const int* __restrict__ ansv, const int* __restrict__ itime,
    const float* __restrict__ ex_t, const float* __restrict__ at_t,
    const float* __restrict__ it_t, const float* __restrict__ WT,
    const float* __restrict__ b1, const float* __restrict__ blv,
    const float* __restrict__ bgv, const float* __restrict__ bfv,
    float* __restrict__ PRE_l, float* __restrict__ PRE_g, float* __restrict__ PRE_f)
{
    __shared__ float leS[9 * 128];
    const int o = threadIdx.x;
    const int p0 = blockIdx.x * NPAIR;

    // ---- le phase: 9 pairs (p0-1 .. p0+7); p<0 clamped (value masked later)
    {
        int eP[9], aP[9];
        float avP[9];
        #pragma unroll
        for (int i = 0; i < 9; ++i) {
            int p = p0 - 1 + i;
            if (p < 0) p = 0;
            int bb = p / T_SZ, tt = p - bb * T_SZ;
            int idx = bb * S_SZ + tt;
            eP[i] = eid[idx];
            aP[i] = atime[idx];
            avP[i] = (float)ansv[idx];
        }
        const float bias = b1[o];
        float acc[9];
        #pragma unroll
        for (int i = 0; i < 9; ++i) acc[i] = bias;
        #pragma unroll 2
        for (int k4 = 0; k4 < 32; ++k4) {
            f32x4 w = *(const f32x4*)(WT + W1T_OFF + (k4 * 128 + o) * 4);
            #pragma unroll
            for (int i = 0; i < 9; ++i)
                acc[i] += dot4(w, *(const f32x4*)(ex_t + eP[i] * DK + 4 * k4));
        }
        #pragma unroll 2
        for (int k4 = 32; k4 < 64; ++k4) {
            f32x4 w = *(const f32x4*)(WT + W1T_OFF + (k4 * 128 + o) * 4);
            #pragma unroll
            for (int i = 0; i < 9; ++i)
                acc[i] += dot4(w, *(const f32x4*)(at_t + aP[i] * DK + 4 * k4 - 128));
        }
        float wsum = 0.f;
        #pragma unroll 4
        for (int k4 = 64; k4 < 96; ++k4) {
            f32x4 w = *(const f32x4*)(WT + W1T_OFF + (k4 * 128 + o) * 4);
            wsum += w[0] + w[1] + w[2] + w[3];
        }
        #pragma unroll
        for (int i = 0; i < 9; ++i)
            leS[i * 128 + o] = acc[i] + avP[i] * wsum;
    }
    __syncthreads();

    // ---- PRE phase: 8 pairs (p0..p0+7); lp = leS[i], lc = leS[i+1]
    int ivP[NPAIR];
    float mP[NPAIR];
    #pragma unroll
    for (int i = 0; i < NPAIR; ++i) {
        int p = p0 + i;
        int bb = p / T_SZ, tt = p - bb * T_SZ;
        ivP[i] = itime[bb * S_SZ + tt + 1];
        mP[i] = (tt == 0) ? 0.f : 1.f;
    }
    const float bl0 = blv[o], bg0 = bgv[o];
    float al[NPAIR], ag[NPAIR];
    #pragma unroll
    for (int i = 0; i < NPAIR; ++i) { al[i] = bl0; ag[i] = bg0; }
    // cols 0:128 -> lp (masked)
    #pragma unroll 2
    for (int k4 = 0; k4 < 32; ++k4) {
        f32x4 w  = *(const f32x4*)(WT + WLT_OFF + (k4 * 128 + o) * 4);
        f32x4 w2 = *(const f32x4*)(WT + WGT_OFF + (k4 * 128 + o) * 4);
        #pragma unroll
        for (int i = 0; i < NPAIR; ++i) {
            f32x4 x = *(const f32x4*)(leS + i * 128 + 4 * k4);
            #pragma unroll
            for (int j = 0; j < 4; ++j) {
                float xv = x[j] * mP[i];
                al[i] += w[j] * xv;
                ag[i] += w2[j] * xv;
            }
        }
    }
    // cols 128:256 -> it
    #pragma unroll 2
    for (int k4 = 32; k4 < 64; ++k4) {
        f32x4 w  = *(const f32x4*)(WT + WLT_OFF + (k4 * 128 + o) * 4);
        f32x4 w2 = *(const f32x4*)(WT + WGT_OFF + (k4 * 128 + o) * 4);
        #pragma unroll
        for (int i = 0; i < NPAIR; ++i) {
            f32x4 x = *(const f32x4*)(it_t + ivP[i] * DK + 4 * k4 - 128);
            #pragma unroll
            for (int j = 0; j < 4; ++j) {
                al[i] += w[j] * x[j];
                ag[i] += w2[j] * x[j];
            }
        }
    }
    // cols 256:384 -> lc
    #pragma unroll 2
    for (int k4 = 64; k4 < 96; ++k4) {
        f32x4 w  = *(const f32x4*)(WT + WLT_OFF + (k4 * 128 + o) * 4);
        f32x4 w2 = *(const f32x4*)(WT + WGT_OFF + (k4 * 128 + o) * 4);
        #pragma unroll
        for (int i = 0; i < NPAIR; ++i) {
            f32x4 x = *(const f32x4*)(leS + (i + 1) * 128 + 4 * k4 - 256);
            #pragma unroll
            for (int j = 0; j < 4; ++j) {
                al[i] += w[j] * x[j];
                ag[i] += w2[j] * x[j];
            }
        }
    }
    // f-gate: Wf cols 256:384 (chunks 64..95) on it
    const float bf0 = bfv[o];
    float af[NPAIR];
    #pragma unroll
    for (int i = 0; i < NPAIR; ++i) af[i] = bf0;
    #pragma unroll 2
    for (int k4 = 0; k4 < 32; ++k4) {
        f32x4 w = *(const f32x4*)(WT + WFT_OFF + ((64 + k4) * 128 + o) * 4);
        #pragma unroll
        for (int i = 0; i < NPAIR; ++i) {
            f32x4 x = *(const f32x4*)(it_t + ivP[i] * DK + 4 * k4);
            af[i] += dot4(w, x);
        }
    }
    #pragma unroll
    for (int i = 0; i < NPAIR; ++i) {
        size_t idx = (size_t)(p0 + i) * DK + o;
        PRE_l[idx] = al[i];
        PRE_g[idx] = ag[i];
        PRE_f[idx] = af[i];
    }
}

// ---------------------------------------------------------------------------
// Kernel C: sequential scan, 4-way skill-split, 8-byte packet exchange.
// EXACT R5/R9 structure (proven 420 us). UNCHANGED.
// ---------------------------------------------------------------------------
__global__ __launch_bounds__(512, 1) void k_main(
    const int* __restrict__ eid, const float* __restrict__ qmat,
    const float* __restrict__ Wl, const float* __restrict__ Wg,
    const float* __restrict__ Wf, const float* __restrict__ h0,
    const float* __restrict__ PRE_l, const float* __restrict__ PRE_g,
    const float* __restrict__ PRE_f, float* __restrict__ ht_ws,
    u64* __restrict__ xbuf)
{
    extern __shared__ char smem[];
    u16*   hS   = (u16*)smem;                    // 64*136*2  = 17408
    float* part = (float*)(smem + 17408);        // 128*68*4  = 34816 -> 52224
    u16*   htbf = (u16*)(smem + 52224);          // hi[128], lo[128] -> 52736
    u16*   LGb  = (u16*)(smem + 52736);          // hi[128], lo[128] -> 53248
    float* LGf  = (float*)(smem + 53248);        // 512 -> 53760
    float* cS   = (float*)(smem + 53760);        // 512 -> 54272

    const int b    = blockIdx.x;
    const int qid  = blockIdx.y;
    const int tid  = threadIdx.x;
    const int w    = tid >> 6;
    const int lane = tid & 63;
    const int quad = lane >> 4;
    const int l4   = lane & 15;
    const int ih   = w & 1;
    const int jh   = w >> 1;

    u64* xq = xbuf + (size_t)b * 1024;
    const int qa = (qid + 1) & 3, qb2 = (qid + 2) & 3, qc = (qid + 3) & 3;

    u16x8 afr[4][4];
    #pragma unroll
    for (int mt = 0; mt < 4; ++mt)
        #pragma unroll
        for (int kt = 0; kt < 4; ++kt) {
            const float* p = Wf + (64 * ih + 16 * mt + l4) * 384 + 32 * kt + quad * 8;
            afr[mt][kt] = cvt8(*(const f32x4*)p, *(const f32x4*)(p + 4));
        }
    u16x8 azf[2][4];
    #pragma unroll
    for (int mt = 0; mt < 2; ++mt)
        #pragma unroll
        for (int kt = 0; kt < 4; ++kt) {
            int d = 16 * w + 8 * mt + (l4 >> 1);
            const float* base = (l4 & 1) ? Wg : Wl;
            const float* p = base + d * 512 + 384 + 32 * kt + quad * 8;
            azf[mt][kt] = cvt8(*(const f32x4*)p, *(const f32x4*)(p + 4));
        }
    u16x8 acf[4];
    #pragma unroll
    for (int kt = 0; kt < 4; ++kt) {
        const float* p = Wf + (16 * w + l4) * 384 + 128 + 32 * kt + quad * 8;
        acf[kt] = cvt8(*(const f32x4*)p, *(const f32x4*)(p + 4));
    }

    const int sl = 16 * jh + l4;
    f32x4 hreg[4];
    #pragma unroll
    for (int mt = 0; mt < 4; ++mt) {
        int d0 = 64 * ih + 16 * mt + quad * 4;
        f32x4 hv = *(const f32x4*)(h0 + (SQTR * qid + sl) * DK + d0);
        hreg[mt] = hv;
        *(u16x4*)(hS + sl * RL + d0) = cvt4(hv);
    }

    float kvt = qmat[eid[b * S_SZ] * SKILL + SQTR * qid + sl];

    f32x4 accF[4];

    {
        float htp[16];
        #pragma unroll
        for (int mt = 0; mt < 4; ++mt)
            #pragma unroll
            for (int r = 0; r < 4; ++r)
                htp[mt * 4 + r] = kvt * hreg[mt][r];
        #pragma unroll
        for (int mt = 0; mt < 4; ++mt)
            #pragma unroll
            for (int r = 0; r < 4; ++r)
                part[(64 * ih + 16 * mt + quad * 4 + r) * PP + jh * 16 + l4] = htp[mt * 4 + r];
        __syncthreads();
        int d = tid >> 2, kq = tid & 3;
        const float* pp = part + d * PP + kq * 16;
        float v = 0.f;
        #pragma unroll
        for (int i4 = 0; i4 < 4; ++i4) {
            f32x4 x = *(const f32x4*)(pp + 4 * i4);
            v += x[0] + x[1] + x[2] + x[3];
        }
        v += __shfl_xor(v, 1, 64);
        v += __shfl_xor(v, 2, 64);
        if (kq == 0) {
            u64 pkt = ((u64)1u << 32) | (u64)__builtin_bit_cast(u32, v);
            __hip_atomic_store(xq + qid * 256 + 128 + d, pkt,
                               __ATOMIC_RELAXED, __HIP_MEMORY_SCOPE_AGENT);
        }
        asm volatile("" ::: "memory");
        #pragma unroll
        for (int mt = 0; mt < 4; ++mt)
            accF[mt] = (f32x4){0.f, 0.f, 0.f, 0.f};
        {
            const u16* bp2 = hS + sl * RL + quad * 8;
            u16x8 bfr[4];
            #pragma unroll
            for (int kt = 0; kt < 4; ++kt) bfr[kt] = *(const u16x8*)(bp2 + kt * 32);
            #pragma unroll
            for (int mt = 0; mt < 4; ++mt)
                #pragma unroll
                for (int kt = 0; kt < 4; ++kt)
                    accF[mt] = mfma16(afr[mt][kt], bfr[kt], accF[mt]);
        }
        if (kq == 0) {
            u64 pa, pb, pc2;
            int spins = 0;
            do {
                pa  = __hip_atomic_load(xq + qa * 256 + 128 + d, __ATOMIC_RELAXED, __HIP_MEMORY_SCOPE_AGENT);
                pb  = __hip_atomic_load(xq + qb2 * 256 + 128 + d, __ATOMIC_RELAXED, __HIP_MEMORY_SCOPE_AGENT);
                pc2 = __hip_atomic_load(xq + qc * 256 + 128 + d, __ATOMIC_RELAXED, __HIP_MEMORY_SCOPE_AGENT);
                if ((u32)(pa >> 32) >= 1u && (u32)(pb >> 32) >= 1u && (u32)(pc2 >> 32) >= 1u) break;
                if (spins > 64) __builtin_amdgcn_s_sleep(1);
            } while (++spins < SPIN_CAP);
            float va = pval(pa), vb = pval(pb), vc = pval(pc2);
            float v0 = (qid == 0) ? v : (qid == 3) ? va : (qid == 2) ? vb : vc;
            float v1 = (qid == 1) ? v : (qid == 0) ? va : (qid == 3) ? vb : vc;
            float v2 = (qid == 2) ? v : (qid == 1) ? va : (qid == 0) ? vb : vc;
            float v3 = (qid == 3) ? v : (qid == 2) ? va : (qid == 1) ? vb : vc;
            float vt = ((v0 + v1) + v2) + v3;
            float hf = (float)(__bf16)vt;
            htbf[d] = bfu(vt);
            htbf[128 + d] = bfu(vt - hf);
        }
        __syncthreads();
    }

    for (int t = 0; t < T_SZ; ++t) {
        const size_t tb = (size_t)(b * T_SZ + t) * DK;
        float kvn = qmat[eid[b * S_SZ + t + 1] * SKILL + SQTR * qid + sl];
        f32x2 pl[2], pg[2];
        #pragma unroll
        for (int mt = 0; mt < 2; ++mt) {
            int d0 = 16 * w + 8 * mt + 2 * quad;
            pl[mt] = *(const f32x2*)(PRE_l + tb + d0);
            pg[mt] = *(const f32x2*)(PRE_g + tb + d0);
        }
        f32x4 pf = *(const f32x4*)(PRE_f + tb + 16 * w + quad * 4);

        f32x4 accZ[2];
        accZ[0] = (f32x4){0.f, 0.f, 0.f, 0.f};
        accZ[1] = (f32x4){0.f, 0.f, 0.f, 0.f};
        #pragma unroll
        for (int kt = 0; kt < 4; ++kt) {
            u16x8 bh = *(const u16x8*)(htbf + 32 * kt + quad * 8);
            u16x8 bl = *(const u16x8*)(htbf + 128 + 32 * kt + quad * 8);
            #pragma unroll
            for (int mt = 0; mt < 2; ++mt) {
                accZ[mt] = mfma16(azf[mt][kt], bh, accZ[mt]);
                accZ[mt] = mfma16(azf[mt][kt], bl, accZ[mt]);
            }
        }
        #pragma unroll
        for (int mt = 0; mt < 2; ++mt) {
            u32 hpack = 0, lpack = 0;
            f32x2 fpack;
            #pragma unroll
            for (int rp = 0; rp < 2; ++rp) {
                float zl = accZ[mt][2 * rp] + pl[mt][rp];
                float zg = accZ[mt][2 * rp + 1] + pg[mt][rp];
                float LGv = sigm(zg) * (tanh_f(zl) + 1.f) * 0.5f;
                float hif = (float)(__bf16)LGv;
                hpack |= ((u32)bfu(LGv)) << (16 * rp);
                lpack |= ((u32)bfu(LGv - hif)) << (16 * rp);
                fpack[rp] = LGv;
            }
            if (l4 == 0) {
                int d0 = 16 * w + 8 * mt + 2 * quad;
                *(u32*)(LGb + d0) = hpack;
                *(u32*)(LGb + 128 + d0) = lpack;
                *(f32x2*)(LGf + d0) = fpack;
            }
        }
        __syncthreads();   // B: LG ready

        {
            f32x4 accC = (f32x4){0.f, 0.f, 0.f, 0.f};
            #pragma unroll
            for (int kt = 0; kt < 4; ++kt) {
                u16x8 bh = *(const u16x8*)(LGb + 32 * kt + quad * 8);
                u16x8 bl = *(const u16x8*)(LGb + 128 + 32 * kt + quad * 8);
                accC = mfma16(acf[kt], bh, accC);
                accC = mfma16(acf[kt], bl, accC);
            }
            accC += pf;
            if (l4 == 0) *(f32x4*)(cS + 16 * w + quad * 4) = accC;
        }
        __syncthreads();   // C: c ready

        float htp[16];
        #pragma unroll
        for (int mt = 0; mt < 4; ++mt) {
            int d0 = 64 * ih + 16 * mt + quad * 4;
            f32x4 lg = *(const f32x4*)(LGf + d0);
            f32x4 cc = *(const f32x4*)(cS + d0);
            f32x4 hv;
            #pragma unroll
            for (int r = 0; r < 4; ++r) {
                float f = sigm(accF[mt][r] + cc[r]);
                float hn = kvt * lg[r] + f * hreg[mt][r];
                hreg[mt][r] = hn;
                htp[mt * 4 + r] = kvn * hn;
                hv[r] = hn;
            }
            *(u16x4*)(hS + sl * RL + d0) = cvt4(hv);
        }
        #pragma unroll
        for (int mt = 0; mt < 4; ++mt)
            #pragma unroll
            for (int r = 0; r < 4; ++r)
                part[(64 * ih + 16 * mt + quad * 4 + r) * PP + jh * 16 + l4] = htp[mt * 4 + r];
        kvt = kvn;
        __syncthreads();   // E: partials + hS(t+1) ready

        {
            int d = tid >> 2, kq = tid & 3;
            const float* pp = part + d * PP + kq * 16;
            float v = 0.f;
            #pragma unroll
            for (int i4 = 0; i4 < 4; ++i4) {
                f32x4 x = *(const f32x4*)(pp + 4 * i4);
                v += x[0] + x[1] + x[2] + x[3];
            }
            v += __shfl_xor(v, 1, 64);
            v += __shfl_xor(v, 2, 64);
            const int slot = t & 1;            // seq = t+2
            const u32 seq = (u32)(t + 2);
            if (kq == 0) {
                u64 pkt = ((u64)seq << 32) | (u64)__builtin_bit_cast(u32, v);
                __hip_atomic_store(xq + qid * 256 + slot * 128 + d, pkt,
                                   __ATOMIC_RELAXED, __HIP_MEMORY_SCOPE_AGENT);
            }
            asm volatile("" ::: "memory");
            #pragma unroll
            for (int mt = 0; mt < 4; ++mt)
                accF[mt] = (f32x4){0.f, 0.f, 0.f, 0.f};
            {
                const u16* bp2 = hS + sl * RL + quad * 8;
                u16x8 bfr[4];
                #pragma unroll
                for (int kt = 0; kt < 4; ++kt) bfr[kt] = *(const u16x8*)(bp2 + kt * 32);
                #pragma unroll
                for (int mt = 0; mt < 4; ++mt)
                    #pragma unroll
                    for (int kt = 0; kt < 4; ++kt)
                        accF[mt] = mfma16(afr[mt][kt], bfr[kt], accF[mt]);
            }
            if (kq == 0) {
                u64 pa, pb, pc2;
                int spins = 0;
                do {
                    pa  = __hip_atomic_load(xq + qa * 256 + slot * 128 + d, __ATOMIC_RELAXED, __HIP_MEMORY_SCOPE_AGENT);
                    pb  = __hip_atomic_load(xq + qb2 * 256 + slot * 128 + d, __ATOMIC_RELAXED, __HIP_MEMORY_SCOPE_AGENT);
                    pc2 = __hip_atomic_load(xq + qc * 256 + slot * 128 + d, __ATOMIC_RELAXED, __HIP_MEMORY_SCOPE_AGENT);
                    if ((u32)(pa >> 32) >= seq && (u32)(pb >> 32) >= seq && (u32)(pc2 >> 32) >= seq) break;
                    if (spins > 64) __builtin_amdgcn_s_sleep(1);
                } while (++spins < SPIN_CAP);
                float va = pval(pa), vb = pval(pb), vc = pval(pc2);
                float v0 = (qid == 0) ? v : (qid == 3) ? va : (qid == 2) ? vb : vc;
                float v1 = (qid == 1) ? v : (qid == 0) ? va : (qid == 3) ? vb : vc;
                float v2 = (qid == 2) ? v : (qid == 1) ? va : (qid == 0) ? vb : vc;
                float v3 = (qid == 3) ? v : (qid == 2) ? va : (qid == 1) ? vb : vc;
                float vt = ((v0 + v1) + v2) + v3;
                float hf = (float)(__bf16)vt;
                htbf[d] = bfu(vt);
                htbf[128 + d] = bfu(vt - hf);
                if (qid == 0) ht_ws[tb + d] = vt;
            }
        }
        __syncthreads();   // TOP: h~ ready
    }
}

// ---------------------------------------------------------------------------
// Kernel D: pred. 128 threads, 8 pairs/thread; coalesced WpT loads.
// ---------------------------------------------------------------------------
__global__ __launch_bounds__(128) void k_pred(
    const int* __restrict__ eid, const float* __restrict__ ex_t,
    const float* __restrict__ WT, const float* __restrict__ bpv,
    const float* __restrict__ ht_ws, float* __restrict__ out)
{
    const int o = threadIdx.x;
    const int p0 = blockIdx.x * NPAIR;
    int eP[NPAIR];
    #pragma unroll
    for (int i = 0; i < NPAIR; ++i) {
        int p = p0 + i, b = p / T_SZ, t = p - b * T_SZ;
        eP[i] = eid[b * S_SZ + t + 1];
    }
    const float bias = bpv[o];
    float acc[NPAIR];
    #pragma unroll
    for (int i = 0; i < NPAIR; ++i) acc[i] = bias;
    #pragma unroll 2
    for (int k4 = 0; k4 < 32; ++k4) {
        f32x4 w = *(const f32x4*)(WT + WPT_OFF + (k4 * 128 + o) * 4);
        #pragma unroll
        for (int i = 0; i < NPAIR; ++i) {
            f32x4 x = *(const f32x4*)(ex_t + eP[i] * DK + 4 * k4);
            acc[i] += dot4(w, x);
        }
    }
    #pragma unroll 2
    for (int k4 = 32; k4 < 64; ++k4) {
        f32x4 w = *(const f32x4*)(WT + WPT_OFF + (k4 * 128 + o) * 4);
        #pragma unroll
        for (int i = 0; i < NPAIR; ++i) {
            f32x4 x = *(const f32x4*)(ht_ws + (size_t)(p0 + i) * DK + 4 * k4 - 128);
            acc[i] += dot4(w, x);
        }
    }
    #pragma unroll
    for (int i = 0; i < NPAIR; ++i)
        out[(size_t)(p0 + i) * DK + o] = sigm(acc[i]);
}

extern "C" void kernel_launch(void* const* d_in, const int* in_sizes, int n_in,
                              void* d_out, int out_size, void* d_ws, size_t ws_size,
                              hipStream_t stream) {
    const int* eid     = (const int*)d_in[0];
    const int* atime   = (const int*)d_in[1];
    const int* itime   = (const int*)d_in[2];
    const int* ansv    = (const int*)d_in[3];
    const float* qmat  = (const float*)d_in[4];
    const float* ex_t  = (const float*)d_in[5];
    const float* at_t  = (const float*)d_in[6];
    const float* it_t  = (const float*)d_in[7];
    const float* W1    = (const float*)d_in[8];
    const float* b1    = (const float*)d_in[9];
    const float* Wl    = (const float*)d_in[10];
    const float* blv   = (const float*)d_in[11];
    const float* Wg    = (const float*)d_in[12];
    const float* bgv   = (const float*)d_in[13];
    const float* Wf    = (const float*)d_in[14];
    const float* bfv   = (const float*)d_in[15];
    const float* Wp    = (const float*)d_in[16];
    const float* bpv   = (const float*)d_in[17];
    const float* h0    = (const float*)d_in[18];
    float* out = (float*)d_out;

    const size_t SZ = (size_t)B_SZ * T_SZ * DK;
    float* wsf   = (float*)d_ws;
    // region [0, SZ): xbuf (256 KiB) + repacked weights WT (1 MiB)
    u64*   xbuf  = (u64*)wsf;                 // 32*4*2*128 u64 = 65536 f32 slots
    float* WT    = wsf + 65536;               // 262144 floats
    float* PRE_l = wsf + SZ;
    float* PRE_g = wsf + 2 * SZ;
    float* PRE_f = wsf + 3 * SZ;
    float* ht_ws = wsf + 4 * SZ;

    hipFuncSetAttribute((const void*)k_main,
                        hipFuncAttributeMaxDynamicSharedMemorySize, 86016);

    // re-arm packet buffer each replay (stale seq from prior replay otherwise)
    hipMemsetAsync(xbuf, 0, (size_t)B_SZ * 1024 * sizeof(u64), stream);
    k_prep<<<dim3(WT_TOTAL / 256), 256, 0, stream>>>(W1, Wl, Wg, Wf, Wp, WT);
    k_pre <<<dim3(508), 128, 0, stream>>>(eid, atime, ansv, itime,
                                          ex_t, at_t, it_t, WT,
                                          b1, blv, bgv, bfv,
                                          PRE_l, PRE_g, PRE_f);
    k_main<<<dim3(B_SZ, 4), 512, 86016, stream>>>(eid, qmat, Wl, Wg, Wf, h0,
                                                  PRE_l, PRE_g, PRE_f, ht_ws,
                                                  xbuf);
    k_pred<<<dim3(508), 128, 0, stream>>>(eid, ex_t, WT, bpv, ht_ws, out);
}